// Round 1
// baseline (427.111 us; speedup 1.0000x reference)
//
#include <hip/hip_runtime.h>
#include <hip/hip_bf16.h>

#define NH 32
#define HD 64
#define DMODEL 2048
#define CTXD 1024
#define NB 2
#define NSEQ 2048
#define NCTX 2048

typedef __attribute__((ext_vector_type(8))) short bf16x8;
typedef __attribute__((ext_vector_type(4))) float f32x4;
typedef __attribute__((ext_vector_type(4))) short s16x4;
typedef __attribute__((ext_vector_type(2))) float f32x2;

__device__ __forceinline__ unsigned short f2b(float f) {
  unsigned int u = __builtin_bit_cast(unsigned int, f);
  u = u + 0x7fffu + ((u >> 16) & 1u);
  return (unsigned short)(u >> 16);
}

__device__ __forceinline__ void async16(const void* g, void* l) {
  __builtin_amdgcn_global_load_lds((const __attribute__((address_space(1))) void*)g,
                                   (__attribute__((address_space(3))) void*)l, 16, 0, 0);
}

// ---------------- cast f32 -> bf16 (vectorized) ----------------
__global__ void k_cast(const float* __restrict__ in, unsigned short* __restrict__ out, int n4) {
  int i = blockIdx.x * blockDim.x + threadIdx.x;
  if (i >= n4) return;
  float4 v = ((const float4*)in)[i];
  s16x4 o;
  o.x = (short)f2b(v.x);
  o.y = (short)f2b(v.y);
  o.z = (short)f2b(v.z);
  o.w = (short)f2b(v.w);
  ((s16x4*)out)[i] = o;
}

// ---------------- transpose + cast: in[R][C] f32 -> out[C][R] bf16 ----------------
__global__ void k_tcast(const float* __restrict__ in, unsigned short* __restrict__ out,
                        int R, int C) {
  __shared__ float t[32][33];
  const int tx = threadIdx.x, ty = threadIdx.y;  // (32, 8)
  const int c0 = blockIdx.x * 32, r0 = blockIdx.y * 32;
#pragma unroll
  for (int j = 0; j < 4; j++)
    t[ty + j * 8][tx] = in[(size_t)(r0 + ty + j * 8) * C + c0 + tx];
  __syncthreads();
#pragma unroll
  for (int j = 0; j < 4; j++)
    out[(size_t)(c0 + ty + j * 8) * R + r0 + tx] = f2b(t[tx][ty + j * 8]);
}

// ---------------- RoPE cos/sin tables: [B*N][P=2][16] float2 ----------------
__global__ void k_ropetab(const float* __restrict__ pos, f32x2* __restrict__ cs) {
  int idx = blockIdx.x * blockDim.x + threadIdx.x;  // NB*NSEQ*2*16 entries
  int i = idx & 15;
  int p = (idx >> 4) & 1;
  int bn = idx >> 5;
  float freq = powf(10000.0f, -(float)i / 16.0f);
  float ang = pos[bn * 2 + p] * freq;
  float s, c;
  sincosf(ang, &s, &c);
  f32x2 r;
  r.x = c;
  r.y = s;
  cs[idx] = r;
}

// ---------------- 128x128 bf16 GEMM, C = A(M,K) * BT(N,K)^T ----------------
// EPI 0: RoPE + *0.125 -> Q[b][h][n][d] bf16
// EPI 1: col<2048: RoPE -> K[b][h][n][d];  col>=2048: plain -> V[b][h][n][d]
// EPI 2: + bias -> f32 out row-major [M][2048]
template <int EPI>
__launch_bounds__(256) __global__
void k_gemm(const unsigned short* __restrict__ A, const unsigned short* __restrict__ BT,
            unsigned short* __restrict__ out0, unsigned short* __restrict__ out1,
            float* __restrict__ foutp, const f32x2* __restrict__ cs,
            const float* __restrict__ bias, int K) {
  __shared__ __align__(1024) unsigned short As[128 * 32];
  __shared__ __align__(1024) unsigned short Bs[128 * 32];
  const int tid = threadIdx.x;
  const int wave = tid >> 6, lane = tid & 63;
  const int g = lane >> 4, lr = lane & 15;
  const int bm = blockIdx.y * 128, bn = blockIdx.x * 128;
  const int wr = wave >> 1, wc = wave & 1;

  f32x4 acc[4][4];
#pragma unroll
  for (int m = 0; m < 4; m++)
#pragma unroll
    for (int n = 0; n < 4; n++) acc[m][n] = (f32x4){0.f, 0.f, 0.f, 0.f};

  for (int kt = 0; kt < K; kt += 32) {
#pragma unroll
    for (int r = 0; r < 2; r++) {
      int seg = tid + r * 256;
      int row = seg >> 2, ko = (seg & 3) << 3;
      async16(A + (size_t)(bm + row) * K + kt + ko, As + (size_t)(r * 4 + wave) * 512);
      async16(BT + (size_t)(bn + row) * K + kt + ko, Bs + (size_t)(r * 4 + wave) * 512);
    }
    __syncthreads();
    bf16x8 af[4], bfr[4];
#pragma unroll
    for (int m = 0; m < 4; m++) {
      af[m] = *(const bf16x8*)(As + (wr * 64 + m * 16 + lr) * 32 + g * 8);
      bfr[m] = *(const bf16x8*)(Bs + (wc * 64 + m * 16 + lr) * 32 + g * 8);
    }
#pragma unroll
    for (int m = 0; m < 4; m++)
#pragma unroll
      for (int n = 0; n < 4; n++)
        acc[m][n] = __builtin_amdgcn_mfma_f32_16x16x32_bf16(af[m], bfr[n], acc[m][n], 0, 0, 0);
    __syncthreads();
  }

  if constexpr (EPI == 2) {
#pragma unroll
    for (int m = 0; m < 4; m++)
#pragma unroll
      for (int n = 0; n < 4; n++)
#pragma unroll
        for (int r2 = 0; r2 < 4; r2++) {
          int row = bm + wr * 64 + m * 16 + g * 4 + r2;
          int col = bn + wc * 64 + n * 16 + lr;
          foutp[(size_t)row * DMODEL + col] = acc[m][n][r2] + bias[col];
        }
  } else {
    const bool dorope = (EPI == 0) || (bn < DMODEL);
#pragma unroll
    for (int m = 0; m < 4; m++)
#pragma unroll
      for (int n = 0; n < 4; n++)
#pragma unroll
        for (int r2 = 0; r2 < 4; r2++) {
          int row = bm + wr * 64 + m * 16 + g * 4 + r2;
          int col = bn + wc * 64 + n * 16 + lr;
          float v = acc[m][n][r2];
          float pv = __shfl_xor(v, 1);  // partner column (col^1)
          int bb = row >> 11, nn = row & (NSEQ - 1);
          if (dorope) {
            int hh = col >> 6, d = col & 63;
            f32x2 sc = cs[((row << 1) + (d >> 5)) * 16 + ((d >> 1) & 15)];
            // even d: x1*c - x2*s ; odd d: x1*s + x2*c  (x1=even elem, x2=odd elem)
            float o = (d & 1) ? (pv * sc.y + v * sc.x) : (v * sc.x - pv * sc.y);
            if constexpr (EPI == 0) o *= 0.125f;  // fold softmax scale into Q
            out0[(((size_t)(bb * NH + hh)) * NSEQ + nn) * HD + d] = f2b(o);
          } else {
            int c2 = col - DMODEL;
            int hh = c2 >> 6, d = c2 & 63;
            out1[(((size_t)(bb * NH + hh)) * NSEQ + nn) * HD + d] = f2b(v);
          }
        }
  }
}

// ---------------- flash attention ----------------
// grid: (NSEQ/64, NH, NB); 256 thr = 4 waves; wave owns 16 q rows.
// Swapped QK^T: S^T = mfma(A=K, B=Q^T) -> lane holds q = lane&15 (stats lane-local).
// PV as out^T = mfma(A=V^T, B=P^T): P^T frags come straight from S^T C-layout.
__launch_bounds__(256) __global__
void k_attn(const unsigned short* __restrict__ Q, const unsigned short* __restrict__ K,
            const unsigned short* __restrict__ V, unsigned short* __restrict__ O) {
  __shared__ __align__(1024) unsigned short Kl[32 * 64];
  __shared__ __align__(1024) unsigned short Vl[32 * 64];
  const int tid = threadIdx.x;
  const int wave = tid >> 6, lane = tid & 63;
  const int g = lane >> 4, lr = lane & 15;
  const int qt = blockIdx.x, h = blockIdx.y, b = blockIdx.z;
  const size_t headoff = ((size_t)(b * NH + h)) * NSEQ * HD;
  const int q0 = qt * 64 + wave * 16;

  bf16x8 qf[2];
#pragma unroll
  for (int ks = 0; ks < 2; ks++)
    qf[ks] = *(const bf16x8*)(Q + headoff + (size_t)(q0 + lr) * HD + ks * 32 + g * 8);

  f32x4 accO[4];
#pragma unroll
  for (int c = 0; c < 4; c++) accO[c] = (f32x4){0.f, 0.f, 0.f, 0.f};
  float mrun = -1e30f, lrun = 0.f;

  // K staged with XOR swizzle (row-stride 128B is 16-way conflict otherwise):
  // pre-swizzle the GLOBAL source, linear gl_lds dest, swizzle on ds_read.
  const int srow = tid >> 3, sch = tid & 7;
  const unsigned short* gKbase = K + headoff + (size_t)srow * HD + ((sch ^ (srow & 7)) << 3);
  const unsigned short* gVbase = V + headoff + (size_t)tid * 8;
  unsigned short* lK = Kl + wave * 512;
  unsigned short* lV = Vl + wave * 512;

  for (int kv0 = 0; kv0 < NCTX; kv0 += 32) {
    async16(gKbase + (size_t)kv0 * HD, lK);
    async16(gVbase + (size_t)kv0 * HD, lV);
    __syncthreads();

    // S^T: rows kv (2 sub-tiles of 16), cols q
    f32x4 s[2];
    s[0] = (f32x4){0.f, 0.f, 0.f, 0.f};
    s[1] = (f32x4){0.f, 0.f, 0.f, 0.f};
#pragma unroll
    for (int sub = 0; sub < 2; sub++) {
#pragma unroll
      for (int ks = 0; ks < 2; ks++) {
        int r = sub * 16 + lr;
        bf16x8 kf = *(const bf16x8*)(Kl + r * 64 + (((ks * 4 + g) ^ (r & 7)) << 3));
        s[sub] = __builtin_amdgcn_mfma_f32_16x16x32_bf16(kf, qf[ks], s[sub], 0, 0, 0);
      }
    }

    // online softmax over this 32-kv tile; q = lr is lane-local, reduce over g.
    float tm = -1e30f;
#pragma unroll
    for (int sub = 0; sub < 2; sub++)
#pragma unroll
      for (int r2 = 0; r2 < 4; r2++) tm = fmaxf(tm, s[sub][r2]);
    tm = fmaxf(tm, __shfl_xor(tm, 16));
    tm = fmaxf(tm, __shfl_xor(tm, 32));
    float mnew = fmaxf(mrun, tm);
    float corr = __expf(mrun - mnew);
    float p[8];
    float ts = 0.f;
#pragma unroll
    for (int sub = 0; sub < 2; sub++)
#pragma unroll
      for (int r2 = 0; r2 < 4; r2++) {
        float e = __expf(s[sub][r2] - mnew);
        p[sub * 4 + r2] = e;
        ts += e;
      }
    ts += __shfl_xor(ts, 16);
    ts += __shfl_xor(ts, 32);
    lrun = lrun * corr + ts;
    mrun = mnew;
#pragma unroll
    for (int c = 0; c < 4; c++)
#pragma unroll
      for (int r2 = 0; r2 < 4; r2++) accO[c][r2] *= corr;

    // P^T B-frag: k-slot j -> kv = 4g + (j&3) + 16*(j>>2)  == p[j] directly
    bf16x8 pb;
#pragma unroll
    for (int j = 0; j < 8; j++) pb[j] = (short)f2b(p[j]);

    // out^T chunks: A-frag = V^T (row d = c*16+lr, same kv slot map)
#pragma unroll
    for (int c = 0; c < 4; c++) {
      bf16x8 vf;
#pragma unroll
      for (int j = 0; j < 8; j++) {
        int kv = 4 * g + (j & 3) + 16 * (j >> 2);
        vf[j] = (short)Vl[kv * HD + c * 16 + lr];
      }
      accO[c] = __builtin_amdgcn_mfma_f32_16x16x32_bf16(vf, pb, accO[c], 0, 0, 0);
    }
    __syncthreads();
  }

  float inv = 1.0f / lrun;
  size_t base = ((size_t)b * NSEQ + q0 + lr) * DMODEL + h * HD;
#pragma unroll
  for (int c = 0; c < 4; c++)
#pragma unroll
    for (int r2 = 0; r2 < 4; r2++)
      O[base + c * 16 + g * 4 + r2] = f2b(accO[c][r2] * inv);
}

extern "C" void kernel_launch(void* const* d_in, const int* in_sizes, int n_in,
                              void* d_out, int out_size, void* d_ws, size_t ws_size,
                              hipStream_t stream) {
  const float* x = (const float*)d_in[0];
  const float* ctx = (const float*)d_in[1];
  const float* pos_map = (const float*)d_in[2];
  const float* ctx_pos = (const float*)d_in[3];
  const float* Wq = (const float*)d_in[4];
  const float* Wkv = (const float*)d_in[5];
  const float* Wout = (const float*)d_in[6];
  const float* bout = (const float*)d_in[7];
  float* outp = (float*)d_out;

  char* ws = (char*)d_ws;
  unsigned short* xbf = (unsigned short*)(ws + 0);           // 16 MB
  unsigned short* ctxbf = (unsigned short*)(ws + 16777216);  // 8 MB
  unsigned short* wqt = (unsigned short*)(ws + 25165824);    // 8 MB  [N][K]
  unsigned short* wkvt = (unsigned short*)(ws + 33554432);   // 8 MB  [4096][1024]
  unsigned short* woutt = (unsigned short*)(ws + 41943040);  // 8 MB
  unsigned short* qbf = (unsigned short*)(ws + 50331648);    // 16 MB [B][H][N][D]
  unsigned short* kbf = (unsigned short*)(ws + 67108864);    // 16 MB
  unsigned short* vbf = (unsigned short*)(ws + 83886080);    // 16 MB
  unsigned short* attnbf = (unsigned short*)(ws + 100663296);// 16 MB [B*N][2048]
  f32x2* csq = (f32x2*)(ws + 117440512);                     // 1 MB
  f32x2* csk = (f32x2*)(ws + 118489088);                     // 1 MB

  k_cast<<<8192, 256, 0, stream>>>(x, xbf, 2097152);
  k_cast<<<4096, 256, 0, stream>>>(ctx, ctxbf, 1048576);
  dim3 tb(32, 8);
  k_tcast<<<dim3(64, 64), tb, 0, stream>>>(Wq, wqt, 2048, 2048);
  k_tcast<<<dim3(128, 32), tb, 0, stream>>>(Wkv, wkvt, 1024, 4096);
  k_tcast<<<dim3(64, 64), tb, 0, stream>>>(Wout, woutt, 2048, 2048);
  k_ropetab<<<512, 256, 0, stream>>>(pos_map, csq);
  k_ropetab<<<512, 256, 0, stream>>>(ctx_pos, csk);

  // Q = rope(x @ Wq) * 0.125 -> [B][H][N][D]
  k_gemm<0><<<dim3(16, 32), 256, 0, stream>>>(xbf, wqt, qbf, nullptr, nullptr, csq, nullptr, 2048);
  // K,V = split(ctx @ Wkv); rope(K) -> [B][H][N][D]
  k_gemm<1><<<dim3(32, 32), 256, 0, stream>>>(ctxbf, wkvt, kbf, vbf, nullptr, csk, nullptr, 1024);
  // attention -> attn_bf [B*N][2048]
  k_attn<<<dim3(32, 32, 2), 256, 0, stream>>>(qbf, kbf, vbf, attnbf);
  // out = attn @ Wout + bout (f32)
  k_gemm<2><<<dim3(16, 32), 256, 0, stream>>>(attnbf, woutt, nullptr, nullptr, outp, nullptr, bout, 2048);
}

// Round 2
// 335.989 us; speedup vs baseline: 1.2712x; 1.2712x over previous
//
#include <hip/hip_runtime.h>
#include <hip/hip_bf16.h>

#define NH 32
#define HD 64
#define DMODEL 2048
#define CTXD 1024
#define NB 2
#define NSEQ 2048
#define NCTX 2048

typedef __attribute__((ext_vector_type(8))) short bf16x8;
typedef __attribute__((ext_vector_type(4))) float f32x4;
typedef __attribute__((ext_vector_type(4))) short s16x4;
typedef __attribute__((ext_vector_type(2))) float f32x2;
typedef __attribute__((ext_vector_type(4))) unsigned int u32x4;

__device__ __forceinline__ unsigned short f2b(float f) {
  unsigned int u = __builtin_bit_cast(unsigned int, f);
  u = u + 0x7fffu + ((u >> 16) & 1u);
  return (unsigned short)(u >> 16);
}

__device__ __forceinline__ unsigned int cvtpk(float lo, float hi) {
  unsigned int r;
  asm("v_cvt_pk_bf16_f32 %0, %1, %2" : "=v"(r) : "v"(lo), "v"(hi));
  return r;
}

__device__ __forceinline__ float exp2a(float x) {  // 2^x via v_exp_f32
  float r;
  asm("v_exp_f32 %0, %1" : "=v"(r) : "v"(x));
  return r;
}

__device__ __forceinline__ void async16(const void* g, void* l) {
  __builtin_amdgcn_global_load_lds((const __attribute__((address_space(1))) void*)g,
                                   (__attribute__((address_space(3))) void*)l, 16, 0, 0);
}

// ---------------- cast f32 -> bf16 (vectorized) ----------------
__global__ void k_cast(const float* __restrict__ in, unsigned short* __restrict__ out, int n4) {
  int i = blockIdx.x * blockDim.x + threadIdx.x;
  if (i >= n4) return;
  float4 v = ((const float4*)in)[i];
  s16x4 o;
  o.x = (short)f2b(v.x);
  o.y = (short)f2b(v.y);
  o.z = (short)f2b(v.z);
  o.w = (short)f2b(v.w);
  ((s16x4*)out)[i] = o;
}

// ---------------- transpose + cast: in[R][C] f32 -> out[C][R] bf16 ----------------
__global__ void k_tcast(const float* __restrict__ in, unsigned short* __restrict__ out,
                        int R, int C) {
  __shared__ float t[32][33];
  const int tx = threadIdx.x, ty = threadIdx.y;  // (32, 8)
  const int c0 = blockIdx.x * 32, r0 = blockIdx.y * 32;
#pragma unroll
  for (int j = 0; j < 4; j++)
    t[ty + j * 8][tx] = in[(size_t)(r0 + ty + j * 8) * C + c0 + tx];
  __syncthreads();
#pragma unroll
  for (int j = 0; j < 4; j++)
    out[(size_t)(c0 + ty + j * 8) * R + r0 + tx] = f2b(t[tx][ty + j * 8]);
}

// ---------------- bf16 transpose V[b][h][n][d] -> VT[b][h][d][n] ----------------
__global__ void k_vtrans(const unsigned short* __restrict__ V, unsigned short* __restrict__ VT) {
  __shared__ unsigned short t[64][65];
  const int tid = threadIdx.x;  // 256
  const int bh = blockIdx.y;    // 64
  const int n0 = blockIdx.x * 64;
  const int rr = tid >> 3, cc = tid & 7;
#pragma unroll
  for (int r = 0; r < 2; ++r) {
    int n = r * 32 + rr;
    bf16x8 v = *(const bf16x8*)(V + ((size_t)bh * NCTX + n0 + n) * HD + cc * 8);
#pragma unroll
    for (int i = 0; i < 8; ++i) t[n][cc * 8 + i] = (unsigned short)v[i];
  }
  __syncthreads();
#pragma unroll
  for (int r = 0; r < 2; ++r) {
    int d = r * 32 + rr;
    bf16x8 o;
#pragma unroll
    for (int i = 0; i < 8; ++i) o[i] = (short)t[cc * 8 + i][d];
    *(bf16x8*)(VT + ((size_t)bh * HD + d) * NCTX + n0 + cc * 8) = o;
  }
}

// ---------------- RoPE cos/sin tables: [B*N][P=2][16] float2 ----------------
__global__ void k_ropetab(const float* __restrict__ pos, f32x2* __restrict__ cs) {
  int idx = blockIdx.x * blockDim.x + threadIdx.x;  // NB*NSEQ*2*16 entries
  int i = idx & 15;
  int p = (idx >> 4) & 1;
  int bn = idx >> 5;
  float freq = powf(10000.0f, -(float)i / 16.0f);
  float ang = pos[bn * 2 + p] * freq;
  float s, c;
  sincosf(ang, &s, &c);
  f32x2 r;
  r.x = c;
  r.y = s;
  cs[idx] = r;
}

// ---------------- 128x128 bf16 GEMM, C = A(M,K) * BT(N,K)^T ----------------
// EPI 0: RoPE + *(0.125*log2e) -> Q[b][h][n][d] bf16   (attn works in 2^x domain)
// EPI 1: col<2048: RoPE -> K[b][h][n][d];  col>=2048: plain -> V[b][h][n][d]
// EPI 2: + bias -> f32 out row-major [M][2048]
template <int EPI>
__launch_bounds__(256) __global__
void k_gemm(const unsigned short* __restrict__ A, const unsigned short* __restrict__ BT,
            unsigned short* __restrict__ out0, unsigned short* __restrict__ out1,
            float* __restrict__ foutp, const f32x2* __restrict__ cs,
            const float* __restrict__ bias, int K) {
  __shared__ __align__(1024) unsigned short As[128 * 32];
  __shared__ __align__(1024) unsigned short Bs[128 * 32];
  const int tid = threadIdx.x;
  const int wave = tid >> 6, lane = tid & 63;
  const int g = lane >> 4, lr = lane & 15;
  const int bm = blockIdx.y * 128, bn = blockIdx.x * 128;
  const int wr = wave >> 1, wc = wave & 1;

  f32x4 acc[4][4];
#pragma unroll
  for (int m = 0; m < 4; m++)
#pragma unroll
    for (int n = 0; n < 4; n++) acc[m][n] = (f32x4){0.f, 0.f, 0.f, 0.f};

  for (int kt = 0; kt < K; kt += 32) {
#pragma unroll
    for (int r = 0; r < 2; r++) {
      int seg = tid + r * 256;
      int row = seg >> 2, ko = (seg & 3) << 3;
      async16(A + (size_t)(bm + row) * K + kt + ko, As + (size_t)(r * 4 + wave) * 512);
      async16(BT + (size_t)(bn + row) * K + kt + ko, Bs + (size_t)(r * 4 + wave) * 512);
    }
    __syncthreads();
    bf16x8 af[4], bfr[4];
#pragma unroll
    for (int m = 0; m < 4; m++) {
      af[m] = *(const bf16x8*)(As + (wr * 64 + m * 16 + lr) * 32 + g * 8);
      bfr[m] = *(const bf16x8*)(Bs + (wc * 64 + m * 16 + lr) * 32 + g * 8);
    }
#pragma unroll
    for (int m = 0; m < 4; m++)
#pragma unroll
      for (int n = 0; n < 4; n++)
        acc[m][n] = __builtin_amdgcn_mfma_f32_16x16x32_bf16(af[m], bfr[n], acc[m][n], 0, 0, 0);
    __syncthreads();
  }

  if constexpr (EPI == 2) {
#pragma unroll
    for (int m = 0; m < 4; m++)
#pragma unroll
      for (int n = 0; n < 4; n++)
#pragma unroll
        for (int r2 = 0; r2 < 4; r2++) {
          int row = bm + wr * 64 + m * 16 + g * 4 + r2;
          int col = bn + wc * 64 + n * 16 + lr;
          foutp[(size_t)row * DMODEL + col] = acc[m][n][r2] + bias[col];
        }
  } else {
    const bool dorope = (EPI == 0) || (bn < DMODEL);
#pragma unroll
    for (int m = 0; m < 4; m++)
#pragma unroll
      for (int n = 0; n < 4; n++)
#pragma unroll
        for (int r2 = 0; r2 < 4; r2++) {
          int row = bm + wr * 64 + m * 16 + g * 4 + r2;
          int col = bn + wc * 64 + n * 16 + lr;
          float v = acc[m][n][r2];
          float pv = __shfl_xor(v, 1);  // partner column (col^1)
          int bb = row >> 11, nn = row & (NSEQ - 1);
          if (dorope) {
            int hh = col >> 6, d = col & 63;
            f32x2 sc = cs[((row << 1) + (d >> 5)) * 16 + ((d >> 1) & 15)];
            float o = (d & 1) ? (pv * sc.y + v * sc.x) : (v * sc.x - pv * sc.y);
            if constexpr (EPI == 0) o *= 0.125f * 1.44269504088896f;  // scale * log2(e)
            out0[(((size_t)(bb * NH + hh)) * NSEQ + nn) * HD + d] = f2b(o);
          } else {
            int c2 = col - DMODEL;
            int hh = c2 >> 6, d = c2 & 63;
            out1[(((size_t)(bb * NH + hh)) * NSEQ + nn) * HD + d] = f2b(v);
          }
        }
  }
}

// ---------------- flash attention v2 ----------------
// grid (NSEQ/128, NH, NB), 256 thr = 4 waves; wave owns 32 q rows (2 subtiles).
// KVBLK=64, double-buffered LDS (2-phase: stage t+1 || compute t, 1 barrier/tile).
// S^T = mfma(K, Q): lane holds q=lr; stats lane-local, reduce over g (2 shfl).
// Softmax in 2^x domain (log2e folded into Q); defer-max THR=8; cvt_pk P->bf16.
// PV: out^T = mfma(V^T, P^T); V^T frags = 2x ds_read_b64 (XOR-swizzled), shared
// across both q subtiles.
__launch_bounds__(256, 4) __global__
void k_attn(const unsigned short* __restrict__ Q, const unsigned short* __restrict__ K,
            const unsigned short* __restrict__ VT, unsigned short* __restrict__ O) {
  __shared__ __align__(1024) unsigned short Kl[2][64 * 64];  // [kv][d], 16B-XOR swizzled
  __shared__ __align__(1024) unsigned short Vl[2][64 * 64];  // [d][kv], 16B-XOR swizzled
  const int tid = threadIdx.x;
  const int wave = tid >> 6, lane = tid & 63;
  const int g = lane >> 4, lr = lane & 15;
  const int h = blockIdx.y, b = blockIdx.z;
  const size_t headoff = ((size_t)(b * NH + h)) * NSEQ * HD;
  const size_t headoffT = ((size_t)(b * NH + h)) * HD * NCTX;
  const int q0 = blockIdx.x * 128 + wave * 32;

  // Q fragments in registers: qf[qsub][ks]
  bf16x8 qf[2][2];
#pragma unroll
  for (int qs = 0; qs < 2; qs++)
#pragma unroll
    for (int ks = 0; ks < 2; ks++)
      qf[qs][ks] = *(const bf16x8*)(Q + headoff + (size_t)(q0 + qs * 16 + lr) * HD + ks * 32 + g * 8);

  f32x4 accO[2][4];
#pragma unroll
  for (int qs = 0; qs < 2; qs++)
#pragma unroll
    for (int c = 0; c < 4; c++) accO[qs][c] = (f32x4){0.f, 0.f, 0.f, 0.f};
  float mrun[2] = {-1e30f, -1e30f};
  float lp[2] = {0.f, 0.f};  // per-lane partial row-sums (reduced over g at the end)

  // Staging source addresses (per-lane, inverse-swizzled; LDS dest stays linear).
  const int srow = tid >> 3;                 // 0..31 (round adds +32)
  const int sbyte = (tid & 7) << 4;          // 16B chunk within 128B row
  const int swz = ((sbyte ^ ((srow & 7) << 4)) >> 1);  // in shorts
  const unsigned short* kSrc = K + headoff + (size_t)srow * HD + swz;
  const unsigned short* vSrc = VT + headoffT + (size_t)srow * NCTX + swz;

  auto stage = [&](int bi, int kv0) {
#pragma unroll
    for (int r = 0; r < 2; ++r) {
      async16(kSrc + (size_t)(kv0 + r * 32) * HD, &Kl[bi][(r * 4 + wave) * 512]);
      async16(vSrc + (size_t)r * 32 * NCTX + kv0, &Vl[bi][(r * 4 + wave) * 512]);
    }
  };

  stage(0, 0);
  __syncthreads();
  int cur = 0;

  for (int t = 0; t < NCTX / 64; ++t) {
    if (t < NCTX / 64 - 1) stage(cur ^ 1, (t + 1) * 64);

    const unsigned short* Kc = &Kl[cur][0];
    const unsigned short* Vc = &Vl[cur][0];

    // ---- S^T = K * Q^T  (rows kv, cols q) ----
    f32x4 s[2][4];
#pragma unroll
    for (int qs = 0; qs < 2; qs++)
#pragma unroll
      for (int sub = 0; sub < 4; sub++) s[qs][sub] = (f32x4){0.f, 0.f, 0.f, 0.f};
#pragma unroll
    for (int sub = 0; sub < 4; ++sub) {
      const int kvr = sub * 16 + lr;
#pragma unroll
      for (int ks = 0; ks < 2; ++ks) {
        bf16x8 kf = *(const bf16x8*)(Kc + kvr * 64 + (((ks * 4 + g) ^ (kvr & 7)) << 3));
        s[0][sub] = __builtin_amdgcn_mfma_f32_16x16x32_bf16(kf, qf[0][ks], s[0][sub], 0, 0, 0);
        s[1][sub] = __builtin_amdgcn_mfma_f32_16x16x32_bf16(kf, qf[1][ks], s[1][sub], 0, 0, 0);
      }
    }

    // ---- online softmax (2^x domain), P -> bf16 frags ----
    bf16x8 pb[2][2];
#pragma unroll
    for (int qs = 0; qs < 2; ++qs) {
      float tm = s[qs][0][0];
#pragma unroll
      for (int sub = 0; sub < 4; sub++)
#pragma unroll
        for (int r2 = 0; r2 < 4; r2++) tm = fmaxf(tm, s[qs][sub][r2]);
      tm = fmaxf(tm, __shfl_xor(tm, 16));
      tm = fmaxf(tm, __shfl_xor(tm, 32));
      if (__any(tm > mrun[qs] + 8.0f)) {  // defer-max: rescale only on real growth
        float mnew = fmaxf(mrun[qs], tm);
        float corr = exp2a(mrun[qs] - mnew);
        lp[qs] *= corr;
#pragma unroll
        for (int c = 0; c < 4; c++) accO[qs][c] *= corr;
        mrun[qs] = mnew;
      }
      float lsum = 0.f;
#pragma unroll
      for (int sub = 0; sub < 4; sub++)
#pragma unroll
        for (int r2 = 0; r2 < 4; r2++) {
          float e = exp2a(s[qs][sub][r2] - mrun[qs]);
          s[qs][sub][r2] = e;
          lsum += e;
        }
      lp[qs] += lsum;
#pragma unroll
      for (int kg = 0; kg < 2; kg++) {
        u32x4 w;
        w.x = cvtpk(s[qs][2 * kg][0], s[qs][2 * kg][1]);
        w.y = cvtpk(s[qs][2 * kg][2], s[qs][2 * kg][3]);
        w.z = cvtpk(s[qs][2 * kg + 1][0], s[qs][2 * kg + 1][1]);
        w.w = cvtpk(s[qs][2 * kg + 1][2], s[qs][2 * kg + 1][3]);
        pb[qs][kg] = __builtin_bit_cast(bf16x8, w);
      }
    }

    // ---- PV: out^T += V^T * P^T (V frags shared across both q subtiles) ----
#pragma unroll
    for (int c = 0; c < 4; ++c) {
      const int d = c * 16 + lr;
#pragma unroll
      for (int kg = 0; kg < 2; ++kg) {
        s16x4 lo = *(const s16x4*)(Vc + d * 64 + ((kg * 32 + 4 * g) ^ ((d & 7) << 3)));
        s16x4 hi = *(const s16x4*)(Vc + d * 64 + ((kg * 32 + 16 + 4 * g) ^ ((d & 7) << 3)));
        bf16x8 vf = __builtin_shufflevector(lo, hi, 0, 1, 2, 3, 4, 5, 6, 7);
        accO[0][c] = __builtin_amdgcn_mfma_f32_16x16x32_bf16(vf, pb[0][kg], accO[0][c], 0, 0, 0);
        accO[1][c] = __builtin_amdgcn_mfma_f32_16x16x32_bf16(vf, pb[1][kg], accO[1][c], 0, 0, 0);
      }
    }
    __syncthreads();
    cur ^= 1;
  }

  // ---- epilogue: finish l-reduce over g, normalize, store bf16 ----
  const size_t obase = (size_t)b * NSEQ * DMODEL + (size_t)h * HD;
#pragma unroll
  for (int qs = 0; qs < 2; ++qs) {
    float l = lp[qs];
    l += __shfl_xor(l, 16);
    l += __shfl_xor(l, 32);
    float inv = 1.0f / l;
    const int q = q0 + qs * 16 + lr;
#pragma unroll
    for (int c = 0; c < 4; ++c) {
      s16x4 o4;
#pragma unroll
      for (int r2 = 0; r2 < 4; r2++) o4[r2] = (short)f2b(accO[qs][c][r2] * inv);
      *(s16x4*)(O + obase + (size_t)q * DMODEL + c * 16 + 4 * g) = o4;
    }
  }
}

extern "C" void kernel_launch(void* const* d_in, const int* in_sizes, int n_in,
                              void* d_out, int out_size, void* d_ws, size_t ws_size,
                              hipStream_t stream) {
  const float* x = (const float*)d_in[0];
  const float* ctx = (const float*)d_in[1];
  const float* pos_map = (const float*)d_in[2];
  const float* ctx_pos = (const float*)d_in[3];
  const float* Wq = (const float*)d_in[4];
  const float* Wkv = (const float*)d_in[5];
  const float* Wout = (const float*)d_in[6];
  const float* bout = (const float*)d_in[7];
  float* outp = (float*)d_out;

  char* ws = (char*)d_ws;
  unsigned short* xbf = (unsigned short*)(ws + 0);           // 16 MB (dead after gemm<0>)
  unsigned short* vtbf = (unsigned short*)(ws + 0);          // 16 MB alias over xbf
  unsigned short* ctxbf = (unsigned short*)(ws + 16777216);  // 8 MB
  unsigned short* wqt = (unsigned short*)(ws + 25165824);    // 8 MB  [N][K]
  unsigned short* wkvt = (unsigned short*)(ws + 33554432);   // 8 MB  [4096][1024]
  unsigned short* woutt = (unsigned short*)(ws + 41943040);  // 8 MB
  unsigned short* qbf = (unsigned short*)(ws + 50331648);    // 16 MB [B][H][N][D]
  unsigned short* kbf = (unsigned short*)(ws + 67108864);    // 16 MB
  unsigned short* vbf = (unsigned short*)(ws + 83886080);    // 16 MB [B][H][N][D]
  unsigned short* attnbf = (unsigned short*)(ws + 100663296);// 16 MB [B*N][2048]
  f32x2* csq = (f32x2*)(ws + 117440512);                     // 1 MB
  f32x2* csk = (f32x2*)(ws + 118489088);                     // 1 MB

  k_cast<<<8192, 256, 0, stream>>>(x, xbf, 2097152);
  k_cast<<<4096, 256, 0, stream>>>(ctx, ctxbf, 1048576);
  dim3 tb(32, 8);
  k_tcast<<<dim3(64, 64), tb, 0, stream>>>(Wq, wqt, 2048, 2048);
  k_tcast<<<dim3(128, 32), tb, 0, stream>>>(Wkv, wkvt, 1024, 4096);
  k_tcast<<<dim3(64, 64), tb, 0, stream>>>(Wout, woutt, 2048, 2048);
  k_ropetab<<<512, 256, 0, stream>>>(pos_map, csq);
  k_ropetab<<<512, 256, 0, stream>>>(ctx_pos, csk);

  // Q = rope(x @ Wq) * 0.125*log2e -> [B][H][N][D]
  k_gemm<0><<<dim3(16, 32), 256, 0, stream>>>(xbf, wqt, qbf, nullptr, nullptr, csq, nullptr, 2048);
  // K,V = split(ctx @ Wkv); rope(K) -> [B][H][N][D]
  k_gemm<1><<<dim3(32, 32), 256, 0, stream>>>(ctxbf, wkvt, kbf, vbf, nullptr, csk, nullptr, 1024);
  // V -> V^T [B][H][D][N]  (xbf is dead now; vtbf aliases it)
  k_vtrans<<<dim3(32, 64), 256, 0, stream>>>(vbf, vtbf);
  // attention -> attn_bf [B*N][2048]
  k_attn<<<dim3(16, 32, 2), 256, 0, stream>>>(qbf, kbf, vtbf, attnbf);
  // out = attn @ Wout + bout (f32)
  k_gemm<2><<<dim3(16, 32), 256, 0, stream>>>(attnbf, woutt, nullptr, nullptr, outp, nullptr, bout, 2048);
}

// Round 3
// 321.697 us; speedup vs baseline: 1.3277x; 1.0444x over previous
//
#include <hip/hip_runtime.h>
#include <hip/hip_bf16.h>

#define NH 32
#define HD 64
#define DMODEL 2048
#define CTXD 1024
#define NB 2
#define NSEQ 2048
#define NCTX 2048

typedef __attribute__((ext_vector_type(8))) short bf16x8;
typedef __attribute__((ext_vector_type(4))) float f32x4;
typedef __attribute__((ext_vector_type(4))) short s16x4;
typedef __attribute__((ext_vector_type(2))) float f32x2;
typedef __attribute__((ext_vector_type(4))) unsigned int u32x4;

__device__ __forceinline__ unsigned short f2b(float f) {
  unsigned int u = __builtin_bit_cast(unsigned int, f);
  u = u + 0x7fffu + ((u >> 16) & 1u);
  return (unsigned short)(u >> 16);
}

__device__ __forceinline__ unsigned int cvtpk(float lo, float hi) {
  unsigned int r;
  asm("v_cvt_pk_bf16_f32 %0, %1, %2" : "=v"(r) : "v"(lo), "v"(hi));
  return r;
}

__device__ __forceinline__ float exp2a(float x) {  // 2^x via v_exp_f32
  float r;
  asm("v_exp_f32 %0, %1" : "=v"(r) : "v"(x));
  return r;
}

__device__ __forceinline__ float max3f(float a, float b, float c) {
  float r;
  asm("v_max3_f32 %0, %1, %2, %3" : "=v"(r) : "v"(a), "v"(b), "v"(c));
  return r;
}

__device__ __forceinline__ void async16(const void* g, void* l) {
  __builtin_amdgcn_global_load_lds((const __attribute__((address_space(1))) void*)g,
                                   (__attribute__((address_space(3))) void*)l, 16, 0, 0);
}

// ---------------- cast f32 -> bf16 (vectorized) ----------------
__global__ void k_cast(const float* __restrict__ in, unsigned short* __restrict__ out, int n4) {
  int i = blockIdx.x * blockDim.x + threadIdx.x;
  if (i >= n4) return;
  float4 v = ((const float4*)in)[i];
  s16x4 o;
  o.x = (short)f2b(v.x);
  o.y = (short)f2b(v.y);
  o.z = (short)f2b(v.z);
  o.w = (short)f2b(v.w);
  ((s16x4*)out)[i] = o;
}

// ---------------- transpose + cast: in[R][C] f32 -> out[C][R] bf16 ----------------
__global__ void k_tcast(const float* __restrict__ in, unsigned short* __restrict__ out,
                        int R, int C) {
  __shared__ float t[32][33];
  const int tx = threadIdx.x, ty = threadIdx.y;  // (32, 8)
  const int c0 = blockIdx.x * 32, r0 = blockIdx.y * 32;
#pragma unroll
  for (int j = 0; j < 4; j++)
    t[ty + j * 8][tx] = in[(size_t)(r0 + ty + j * 8) * C + c0 + tx];
  __syncthreads();
#pragma unroll
  for (int j = 0; j < 4; j++)
    out[(size_t)(c0 + ty + j * 8) * R + r0 + tx] = f2b(t[tx][ty + j * 8]);
}

// ---------------- V[b][h][n][d] -> Vtile[b][h][ntile][d][i2] ----------------
// Tile-blocked transposed V with the PV A-fragment k-slot permutation AND the
// LDS bank-swizzle XOR baked in:
//   i2 = i ^ ((d&7)<<3),  kv(i) = 32*(i>>5) + 4*((i>>3)&3) + (i&3) + 16*((i>>2)&1)
// so attn staging is a plain linear copy and each V-frag is one b128 read.
__global__ void k_vtrans(const unsigned short* __restrict__ V, unsigned short* __restrict__ VT) {
  __shared__ unsigned short t[64][65];
  const int tid = threadIdx.x;  // 256
  const int bh = blockIdx.y;    // 64
  const int n0 = blockIdx.x * 64;
  const int rr = tid >> 3, cc = tid & 7;
#pragma unroll
  for (int r = 0; r < 2; ++r) {
    int n = r * 32 + rr;
    bf16x8 v = *(const bf16x8*)(V + ((size_t)bh * NCTX + n0 + n) * HD + cc * 8);
#pragma unroll
    for (int i = 0; i < 8; ++i) t[n][cc * 8 + i] = (unsigned short)v[i];
  }
  __syncthreads();
#pragma unroll
  for (int r = 0; r < 2; ++r) {
    int d = r * 32 + rr;
    int sc = cc ^ (d & 7);  // source chunk index (XOR is chunk-granular)
    int kvb = 32 * (sc >> 2) + 4 * (sc & 3);
    bf16x8 o;
#pragma unroll
    for (int j = 0; j < 8; ++j) {
      int kv = kvb + (j & 3) + 16 * ((j >> 2) & 1);
      o[j] = (short)t[kv][d];
    }
    *(bf16x8*)(VT + (size_t)bh * (NCTX * HD) + (size_t)blockIdx.x * 4096 + d * 64 + cc * 8) = o;
  }
}

// ---------------- RoPE cos/sin tables: [B*N][P=2][16] float2 ----------------
__global__ void k_ropetab(const float* __restrict__ pos, f32x2* __restrict__ cs) {
  int idx = blockIdx.x * blockDim.x + threadIdx.x;  // NB*NSEQ*2*16 entries
  int i = idx & 15;
  int p = (idx >> 4) & 1;
  int bn = idx >> 5;
  float freq = powf(10000.0f, -(float)i / 16.0f);
  float ang = pos[bn * 2 + p] * freq;
  float s, c;
  sincosf(ang, &s, &c);
  f32x2 r;
  r.x = c;
  r.y = s;
  cs[idx] = r;
}

// ---------------- 128x128 bf16 GEMM, C = A(M,K) * BT(N,K)^T ----------------
// EPI 0: RoPE + *(0.125*log2e) -> Q[b][h][n][d] bf16   (attn works in 2^x domain)
// EPI 1: col<2048: RoPE -> K[b][h][n][d];  col>=2048: plain -> V[b][h][n][d]
// EPI 2: + bias -> f32 out row-major [M][2048]
template <int EPI>
__launch_bounds__(256) __global__
void k_gemm(const unsigned short* __restrict__ A, const unsigned short* __restrict__ BT,
            unsigned short* __restrict__ out0, unsigned short* __restrict__ out1,
            float* __restrict__ foutp, const f32x2* __restrict__ cs,
            const float* __restrict__ bias, int K) {
  __shared__ __align__(1024) unsigned short As[128 * 32];
  __shared__ __align__(1024) unsigned short Bs[128 * 32];
  const int tid = threadIdx.x;
  const int wave = tid >> 6, lane = tid & 63;
  const int g = lane >> 4, lr = lane & 15;
  const int bm = blockIdx.y * 128, bn = blockIdx.x * 128;
  const int wr = wave >> 1, wc = wave & 1;

  f32x4 acc[4][4];
#pragma unroll
  for (int m = 0; m < 4; m++)
#pragma unroll
    for (int n = 0; n < 4; n++) acc[m][n] = (f32x4){0.f, 0.f, 0.f, 0.f};

  for (int kt = 0; kt < K; kt += 32) {
#pragma unroll
    for (int r = 0; r < 2; r++) {
      int seg = tid + r * 256;
      int row = seg >> 2, ko = (seg & 3) << 3;
      async16(A + (size_t)(bm + row) * K + kt + ko, As + (size_t)(r * 4 + wave) * 512);
      async16(BT + (size_t)(bn + row) * K + kt + ko, Bs + (size_t)(r * 4 + wave) * 512);
    }
    __syncthreads();
    bf16x8 af[4], bfr[4];
#pragma unroll
    for (int m = 0; m < 4; m++) {
      af[m] = *(const bf16x8*)(As + (wr * 64 + m * 16 + lr) * 32 + g * 8);
      bfr[m] = *(const bf16x8*)(Bs + (wc * 64 + m * 16 + lr) * 32 + g * 8);
    }
#pragma unroll
    for (int m = 0; m < 4; m++)
#pragma unroll
      for (int n = 0; n < 4; n++)
        acc[m][n] = __builtin_amdgcn_mfma_f32_16x16x32_bf16(af[m], bfr[n], acc[m][n], 0, 0, 0);
    __syncthreads();
  }

  if constexpr (EPI == 2) {
#pragma unroll
    for (int m = 0; m < 4; m++)
#pragma unroll
      for (int n = 0; n < 4; n++)
#pragma unroll
        for (int r2 = 0; r2 < 4; r2++) {
          int row = bm + wr * 64 + m * 16 + g * 4 + r2;
          int col = bn + wc * 64 + n * 16 + lr;
          foutp[(size_t)row * DMODEL + col] = acc[m][n][r2] + bias[col];
        }
  } else {
    const bool dorope = (EPI == 0) || (bn < DMODEL);
#pragma unroll
    for (int m = 0; m < 4; m++)
#pragma unroll
      for (int n = 0; n < 4; n++)
#pragma unroll
        for (int r2 = 0; r2 < 4; r2++) {
          int row = bm + wr * 64 + m * 16 + g * 4 + r2;
          int col = bn + wc * 64 + n * 16 + lr;
          float v = acc[m][n][r2];
          float pv = __shfl_xor(v, 1);  // partner column (col^1)
          int bb = row >> 11, nn = row & (NSEQ - 1);
          if (dorope) {
            int hh = col >> 6, d = col & 63;
            f32x2 sc = cs[((row << 1) + (d >> 5)) * 16 + ((d >> 1) & 15)];
            float o = (d & 1) ? (pv * sc.y + v * sc.x) : (v * sc.x - pv * sc.y);
            if constexpr (EPI == 0) o *= 0.125f * 1.44269504088896f;  // scale * log2(e)
            out0[(((size_t)(bb * NH + hh)) * NSEQ + nn) * HD + d] = f2b(o);
          } else {
            int c2 = col - DMODEL;
            int hh = c2 >> 6, d = c2 & 63;
            out1[(((size_t)(bb * NH + hh)) * NSEQ + nn) * HD + d] = f2b(v);
          }
        }
  }
}

// ---------------- flash attention v3 ----------------
// grid 1024 (1D, XCD-swizzled so all 16 q-blocks of a (b,h) share an XCD's L2).
// 256 thr = 4 waves; wave owns 32 q rows (2 subtiles). KVBLK=64, dbuf LDS.
// S^T = mfma(K, Q): q=lr lane-local. Softmax in 2^x domain; defer-max THR=8;
// max via v_max3 tree; row-sum l via ones-MFMA (accL) on the idle MFMA pipe.
// PV: out^T = mfma(V^T, P^T); V-frags are single b128 reads from the
// permuted+swizzled Vtile layout. setprio(1) around both MFMA clusters.
__launch_bounds__(256, 4) __global__
void k_attn(const unsigned short* __restrict__ Q, const unsigned short* __restrict__ K,
            const unsigned short* __restrict__ VT, unsigned short* __restrict__ O) {
  __shared__ __align__(1024) unsigned short Kl[2][64 * 64];  // [kv][d], 16B-XOR swizzled
  __shared__ __align__(1024) unsigned short Vl[2][64 * 64];  // baked-permuted V tiles
  const int tid = threadIdx.x;
  const int wave = tid >> 6, lane = tid & 63;
  const int g = lane >> 4, lr = lane & 15;
  const int wid = ((blockIdx.x & 7) << 7) + (blockIdx.x >> 3);  // XCD swizzle (1024%8==0)
  const int qt = wid & 15, h = (wid >> 4) & 31, b = wid >> 9;
  const int bh = b * NH + h;
  const size_t headoff = (size_t)bh * NSEQ * HD;
  const int q0 = qt * 128 + wave * 32;

  // Q fragments in registers: qf[qsub][ks]
  bf16x8 qf[2][2];
#pragma unroll
  for (int qs = 0; qs < 2; qs++)
#pragma unroll
    for (int ks = 0; ks < 2; ks++)
      qf[qs][ks] = *(const bf16x8*)(Q + headoff + (size_t)(q0 + qs * 16 + lr) * HD + ks * 32 + g * 8);

  f32x4 accO[2][4];
#pragma unroll
  for (int qs = 0; qs < 2; qs++)
#pragma unroll
    for (int c = 0; c < 4; c++) accO[qs][c] = (f32x4){0.f, 0.f, 0.f, 0.f};
  f32x4 accL[2] = {(f32x4){0.f, 0.f, 0.f, 0.f}, (f32x4){0.f, 0.f, 0.f, 0.f}};
  float mrun[2] = {-1e30f, -1e30f};

  const unsigned short c1 = 0x3F80;  // bf16 1.0
  const bf16x8 ones = {(short)c1, (short)c1, (short)c1, (short)c1,
                       (short)c1, (short)c1, (short)c1, (short)c1};

  // K staged with inverse-swizzled per-lane global source (LDS dest linear);
  // V tiles are pre-permuted+swizzled in global, so V staging is linear.
  const int srow = tid >> 3;
  const unsigned short* kSrc = K + headoff + (size_t)srow * HD + (((tid & 7) ^ (srow & 7)) << 3);
  const unsigned short* vSrc = VT + (size_t)bh * (NCTX * HD) + tid * 8;

  auto stage = [&](int bi, int kv0) {
#pragma unroll
    for (int r = 0; r < 2; ++r) {
      async16(kSrc + (size_t)(kv0 + r * 32) * HD, &Kl[bi][(r * 4 + wave) * 512]);
      async16(vSrc + (size_t)kv0 * 64 + r * 2048, &Vl[bi][(r * 4 + wave) * 512]);
    }
  };

  stage(0, 0);
  __syncthreads();
  int cur = 0;

  for (int t = 0; t < NCTX / 64; ++t) {
    if (t < NCTX / 64 - 1) stage(cur ^ 1, (t + 1) * 64);

    const unsigned short* Kc = &Kl[cur][0];
    const unsigned short* Vc = &Vl[cur][0];

    // ---- S^T = K * Q^T  (rows kv, cols q) ----
    f32x4 s[2][4];
#pragma unroll
    for (int qs = 0; qs < 2; qs++)
#pragma unroll
      for (int sub = 0; sub < 4; sub++) s[qs][sub] = (f32x4){0.f, 0.f, 0.f, 0.f};
    __builtin_amdgcn_s_setprio(1);
#pragma unroll
    for (int sub = 0; sub < 4; ++sub) {
      const int kvr = sub * 16 + lr;
#pragma unroll
      for (int ks = 0; ks < 2; ++ks) {
        bf16x8 kf = *(const bf16x8*)(Kc + kvr * 64 + (((ks * 4 + g) ^ (kvr & 7)) << 3));
        s[0][sub] = __builtin_amdgcn_mfma_f32_16x16x32_bf16(kf, qf[0][ks], s[0][sub], 0, 0, 0);
        s[1][sub] = __builtin_amdgcn_mfma_f32_16x16x32_bf16(kf, qf[1][ks], s[1][sub], 0, 0, 0);
      }
    }
    __builtin_amdgcn_s_setprio(0);

    // ---- online softmax (2^x domain), P -> bf16 frags ----
    bf16x8 pb[2][2];
#pragma unroll
    for (int qs = 0; qs < 2; ++qs) {
      float t0 = max3f(s[qs][0][0], s[qs][0][1], s[qs][0][2]);
      float t1 = max3f(s[qs][0][3], s[qs][1][0], s[qs][1][1]);
      float t2 = max3f(s[qs][1][2], s[qs][1][3], s[qs][2][0]);
      float t3 = max3f(s[qs][2][1], s[qs][2][2], s[qs][2][3]);
      float t4 = max3f(s[qs][3][0], s[qs][3][1], s[qs][3][2]);
      float u0 = max3f(t0, t1, s[qs][3][3]);
      float u1 = max3f(t2, t3, t4);
      float tm = fmaxf(u0, u1);
      tm = fmaxf(tm, __shfl_xor(tm, 16));
      tm = fmaxf(tm, __shfl_xor(tm, 32));
      if (__any(tm > mrun[qs] + 8.0f)) {  // defer-max: rescale only on real growth
        float mnew = fmaxf(mrun[qs], tm);
        float corr = exp2a(mrun[qs] - mnew);
        accL[qs] *= corr;
#pragma unroll
        for (int c = 0; c < 4; c++) accO[qs][c] *= corr;
        mrun[qs] = mnew;
      }
#pragma unroll
      for (int sub = 0; sub < 4; sub++)
#pragma unroll
        for (int r2 = 0; r2 < 4; r2++) s[qs][sub][r2] = exp2a(s[qs][sub][r2] - mrun[qs]);
#pragma unroll
      for (int kg = 0; kg < 2; kg++) {
        u32x4 w;
        w.x = cvtpk(s[qs][2 * kg][0], s[qs][2 * kg][1]);
        w.y = cvtpk(s[qs][2 * kg][2], s[qs][2 * kg][3]);
        w.z = cvtpk(s[qs][2 * kg + 1][0], s[qs][2 * kg + 1][1]);
        w.w = cvtpk(s[qs][2 * kg + 1][2], s[qs][2 * kg + 1][3]);
        pb[qs][kg] = __builtin_bit_cast(bf16x8, w);
      }
    }

    // ---- PV: out^T += V^T * P^T;  l += 1^T * P^T (ones-MFMA) ----
    __builtin_amdgcn_s_setprio(1);
#pragma unroll
    for (int c = 0; c < 4; ++c) {
      const int d = c * 16 + lr;
#pragma unroll
      for (int kg = 0; kg < 2; ++kg) {
        bf16x8 vf = *(const bf16x8*)(Vc + d * 64 + ((kg * 32 + g * 8) ^ ((d & 7) << 3)));
        accO[0][c] = __builtin_amdgcn_mfma_f32_16x16x32_bf16(vf, pb[0][kg], accO[0][c], 0, 0, 0);
        accO[1][c] = __builtin_amdgcn_mfma_f32_16x16x32_bf16(vf, pb[1][kg], accO[1][c], 0, 0, 0);
      }
    }
    accL[0] = __builtin_amdgcn_mfma_f32_16x16x32_bf16(ones, pb[0][0], accL[0], 0, 0, 0);
    accL[0] = __builtin_amdgcn_mfma_f32_16x16x32_bf16(ones, pb[0][1], accL[0], 0, 0, 0);
    accL[1] = __builtin_amdgcn_mfma_f32_16x16x32_bf16(ones, pb[1][0], accL[1], 0, 0, 0);
    accL[1] = __builtin_amdgcn_mfma_f32_16x16x32_bf16(ones, pb[1][1], accL[1], 0, 0, 0);
    __builtin_amdgcn_s_setprio(0);
    __syncthreads();
    cur ^= 1;
  }

  // ---- epilogue: normalize (accL holds full row-sum, replicated), store bf16 ----
  const size_t obase = (size_t)b * NSEQ * DMODEL + (size_t)h * HD;
#pragma unroll
  for (int qs = 0; qs < 2; ++qs) {
    float inv = 1.0f / accL[qs][0];
    const int q = q0 + qs * 16 + lr;
#pragma unroll
    for (int c = 0; c < 4; ++c) {
      s16x4 o4;
#pragma unroll
      for (int r2 = 0; r2 < 4; r2++) o4[r2] = (short)f2b(accO[qs][c][r2] * inv);
      *(s16x4*)(O + obase + (size_t)q * DMODEL + c * 16 + 4 * g) = o4;
    }
  }
}

extern "C" void kernel_launch(void* const* d_in, const int* in_sizes, int n_in,
                              void* d_out, int out_size, void* d_ws, size_t ws_size,
                              hipStream_t stream) {
  const float* x = (const float*)d_in[0];
  const float* ctx = (const float*)d_in[1];
  const float* pos_map = (const float*)d_in[2];
  const float* ctx_pos = (const float*)d_in[3];
  const float* Wq = (const float*)d_in[4];
  const float* Wkv = (const float*)d_in[5];
  const float* Wout = (const float*)d_in[6];
  const float* bout = (const float*)d_in[7];
  float* outp = (float*)d_out;

  char* ws = (char*)d_ws;
  unsigned short* xbf = (unsigned short*)(ws + 0);           // 16 MB (dead after gemm<0>)
  unsigned short* vtbf = (unsigned short*)(ws + 0);          // 16 MB alias over xbf
  unsigned short* ctxbf = (unsigned short*)(ws + 16777216);  // 8 MB
  unsigned short* wqt = (unsigned short*)(ws + 25165824);    // 8 MB  [N][K]
  unsigned short* wkvt = (unsigned short*)(ws + 33554432);   // 8 MB  [4096][1024]
  unsigned short* woutt = (unsigned short*)(ws + 41943040);  // 8 MB
  unsigned short* qbf = (unsigned short*)(ws + 50331648);    // 16 MB [B][H][N][D]
  unsigned short* kbf = (unsigned short*)(ws + 67108864);    // 16 MB
  unsigned short* vbf = (unsigned short*)(ws + 83886080);    // 16 MB [B][H][N][D]
  unsigned short* attnbf = (unsigned short*)(ws + 100663296);// 16 MB [B*N][2048]
  f32x2* csq = (f32x2*)(ws + 117440512);                     // 1 MB
  f32x2* csk = (f32x2*)(ws + 118489088);                     // 1 MB

  k_cast<<<8192, 256, 0, stream>>>(x, xbf, 2097152);
  k_cast<<<4096, 256, 0, stream>>>(ctx, ctxbf, 1048576);
  dim3 tb(32, 8);
  k_tcast<<<dim3(64, 64), tb, 0, stream>>>(Wq, wqt, 2048, 2048);
  k_tcast<<<dim3(128, 32), tb, 0, stream>>>(Wkv, wkvt, 1024, 4096);
  k_tcast<<<dim3(64, 64), tb, 0, stream>>>(Wout, woutt, 2048, 2048);
  k_ropetab<<<512, 256, 0, stream>>>(pos_map, csq);
  k_ropetab<<<512, 256, 0, stream>>>(ctx_pos, csk);

  // Q = rope(x @ Wq) * 0.125*log2e -> [B][H][N][D]
  k_gemm<0><<<dim3(16, 32), 256, 0, stream>>>(xbf, wqt, qbf, nullptr, nullptr, csq, nullptr, 2048);
  // K,V = split(ctx @ Wkv); rope(K) -> [B][H][N][D]
  k_gemm<1><<<dim3(32, 32), 256, 0, stream>>>(ctxbf, wkvt, kbf, vbf, nullptr, csk, nullptr, 1024);
  // V -> permuted+swizzled V tiles (xbf is dead now; vtbf aliases it)
  k_vtrans<<<dim3(32, 64), 256, 0, stream>>>(vbf, vtbf);
  // attention -> attn_bf [B*N][2048]
  k_attn<<<1024, 256, 0, stream>>>(qbf, kbf, vtbf, attnbf);
  // out = attn @ Wout + bout (f32)
  k_gemm<2><<<dim3(16, 32), 256, 0, stream>>>(attnbf, woutt, nullptr, nullptr, outp, nullptr, bout, 2048);
}

// Round 4
// 297.343 us; speedup vs baseline: 1.4364x; 1.0819x over previous
//
#include <hip/hip_runtime.h>
#include <hip/hip_bf16.h>

#define NH 32
#define HD 64
#define DMODEL 2048
#define CTXD 1024
#define NB 2
#define NSEQ 2048
#define NCTX 2048

typedef __attribute__((ext_vector_type(8))) short bf16x8;
typedef __attribute__((ext_vector_type(4))) float f32x4;
typedef __attribute__((ext_vector_type(4))) short s16x4;
typedef __attribute__((ext_vector_type(2))) float f32x2;
typedef __attribute__((ext_vector_type(4))) unsigned int u32x4;

__device__ __forceinline__ unsigned short f2b(float f) {
  unsigned int u = __builtin_bit_cast(unsigned int, f);
  u = u + 0x7fffu + ((u >> 16) & 1u);
  return (unsigned short)(u >> 16);
}

__device__ __forceinline__ unsigned int cvtpk(float lo, float hi) {
  unsigned int r;
  asm("v_cvt_pk_bf16_f32 %0, %1, %2" : "=v"(r) : "v"(lo), "v"(hi));
  return r;
}

__device__ __forceinline__ float exp2a(float x) {  // 2^x via v_exp_f32
  float r;
  asm("v_exp_f32 %0, %1" : "=v"(r) : "v"(x));
  return r;
}

__device__ __forceinline__ float max3f(float a, float b, float c) {
  float r;
  asm("v_max3_f32 %0, %1, %2, %3" : "=v"(r) : "v"(a), "v"(b), "v"(c));
  return r;
}

__device__ __forceinline__ void async16(const void* g, void* l) {
  __builtin_amdgcn_global_load_lds((const __attribute__((address_space(1))) void*)g,
                                   (__attribute__((address_space(3))) void*)l, 16, 0, 0);
}

// ---------------- cast f32 -> bf16 (vectorized) ----------------
__global__ void k_cast(const float* __restrict__ in, unsigned short* __restrict__ out, int n4) {
  int i = blockIdx.x * blockDim.x + threadIdx.x;
  if (i >= n4) return;
  float4 v = ((const float4*)in)[i];
  s16x4 o;
  o.x = (short)f2b(v.x);
  o.y = (short)f2b(v.y);
  o.z = (short)f2b(v.z);
  o.w = (short)f2b(v.w);
  ((s16x4*)out)[i] = o;
}

// ---------------- transpose + cast: in[R][C] f32 -> out[C][R] bf16 ----------------
__global__ void k_tcast(const float* __restrict__ in, unsigned short* __restrict__ out,
                        int R, int C) {
  __shared__ float t[32][33];
  const int tx = threadIdx.x, ty = threadIdx.y;  // (32, 8)
  const int c0 = blockIdx.x * 32, r0 = blockIdx.y * 32;
#pragma unroll
  for (int j = 0; j < 4; j++)
    t[ty + j * 8][tx] = in[(size_t)(r0 + ty + j * 8) * C + c0 + tx];
  __syncthreads();
#pragma unroll
  for (int j = 0; j < 4; j++)
    out[(size_t)(c0 + ty + j * 8) * R + r0 + tx] = f2b(t[tx][ty + j * 8]);
}

// ---------------- V[b][h][n][d] -> Vtile[b][h][ntile][d][i2] ----------------
// Tile-blocked transposed V with the PV A-fragment k-slot permutation AND the
// LDS bank-swizzle XOR baked in:
//   i2 = i ^ ((d&7)<<3),  kv(i) = 32*(i>>5) + 4*((i>>3)&3) + (i&3) + 16*((i>>2)&1)
// so attn staging is a plain linear copy and each V-frag is one b128 read.
__global__ void k_vtrans(const unsigned short* __restrict__ V, unsigned short* __restrict__ VT) {
  __shared__ unsigned short t[64][65];
  const int tid = threadIdx.x;  // 256
  const int bh = blockIdx.y;    // 64
  const int n0 = blockIdx.x * 64;
  const int rr = tid >> 3, cc = tid & 7;
#pragma unroll
  for (int r = 0; r < 2; ++r) {
    int n = r * 32 + rr;
    bf16x8 v = *(const bf16x8*)(V + ((size_t)bh * NCTX + n0 + n) * HD + cc * 8);
#pragma unroll
    for (int i = 0; i < 8; ++i) t[n][cc * 8 + i] = (unsigned short)v[i];
  }
  __syncthreads();
#pragma unroll
  for (int r = 0; r < 2; ++r) {
    int d = r * 32 + rr;
    int sc = cc ^ (d & 7);  // source chunk index (XOR is chunk-granular)
    int kvb = 32 * (sc >> 2) + 4 * (sc & 3);
    bf16x8 o;
#pragma unroll
    for (int j = 0; j < 8; ++j) {
      int kv = kvb + (j & 3) + 16 * ((j >> 2) & 1);
      o[j] = (short)t[kv][d];
    }
    *(bf16x8*)(VT + (size_t)bh * (NCTX * HD) + (size_t)blockIdx.x * 4096 + d * 64 + cc * 8) = o;
  }
}

// ---------------- RoPE cos/sin tables: [B*N][P=2][16] float2 ----------------
__global__ void k_ropetab(const float* __restrict__ pos, f32x2* __restrict__ cs) {
  int idx = blockIdx.x * blockDim.x + threadIdx.x;  // NB*NSEQ*2*16 entries
  int i = idx & 15;
  int p = (idx >> 4) & 1;
  int bn = idx >> 5;
  float freq = powf(10000.0f, -(float)i / 16.0f);
  float ang = pos[bn * 2 + p] * freq;
  float s, c;
  sincosf(ang, &s, &c);
  f32x2 r;
  r.x = c;
  r.y = s;
  cs[idx] = r;
}

// ---------------- 128x128 bf16 GEMM v2: 2-phase double-buffered ----------------
// C = A(M,K) * BT(N,K)^T.  K-loop: STAGE(buf^1, t+1) issued FIRST, then
// ds_read+MFMA on buf[cur] (setprio), then ONE __syncthreads() whose implicit
// vmcnt(0)+lgkmcnt(0) drain doubles as the pipeline wait (T3-minimum recipe).
// EPI 0: RoPE + *(0.125*log2e) -> Q[b][h][n][d] bf16   (attn works in 2^x domain)
// EPI 1: col<2048: RoPE -> K[b][h][n][d];  col>=2048: plain -> V[b][h][n][d]
// EPI 2: + bias -> f32 out row-major [M][2048]
template <int EPI>
__launch_bounds__(256) __global__
void k_gemm(const unsigned short* __restrict__ A, const unsigned short* __restrict__ BT,
            unsigned short* __restrict__ out0, unsigned short* __restrict__ out1,
            float* __restrict__ foutp, const f32x2* __restrict__ cs,
            const float* __restrict__ bias, int K) {
  __shared__ __align__(1024) unsigned short As[2][128 * 32];
  __shared__ __align__(1024) unsigned short Bs[2][128 * 32];
  const int tid = threadIdx.x;
  const int wave = tid >> 6, lane = tid & 63;
  const int g = lane >> 4, lr = lane & 15;
  const int bm = blockIdx.y * 128, bn = blockIdx.x * 128;
  const int wr = wave >> 1, wc = wave & 1;

  f32x4 acc[4][4];
#pragma unroll
  for (int m = 0; m < 4; m++)
#pragma unroll
    for (int n = 0; n < 4; n++) acc[m][n] = (f32x4){0.f, 0.f, 0.f, 0.f};

  // Per-thread staging coords: rep r covers rows r*64..r*64+63.
  const int row0 = tid >> 2, ko0 = (tid & 3) << 3;
  const unsigned short* aSrc = A + (size_t)(bm + row0) * K + ko0;
  const unsigned short* bSrc = BT + (size_t)(bn + row0) * K + ko0;
  const size_t rstep = (size_t)64 * K;  // rep 1 source offset

  auto stage = [&](int bi, int kt) {
    async16(aSrc + kt, &As[bi][(0 * 4 + wave) * 512]);
    async16(bSrc + kt, &Bs[bi][(0 * 4 + wave) * 512]);
    async16(aSrc + rstep + kt, &As[bi][(1 * 4 + wave) * 512]);
    async16(bSrc + rstep + kt, &Bs[bi][(1 * 4 + wave) * 512]);
  };

  stage(0, 0);
  __syncthreads();
  int cur = 0;
  const int NT = K >> 5;

  for (int t = 0; t < NT; ++t) {
    if (t < NT - 1) stage(cur ^ 1, (t + 1) * 32);
    bf16x8 af[4], bfr[4];
#pragma unroll
    for (int m = 0; m < 4; m++) {
      af[m] = *(const bf16x8*)(&As[cur][(wr * 64 + m * 16 + lr) * 32 + g * 8]);
      bfr[m] = *(const bf16x8*)(&Bs[cur][(wc * 64 + m * 16 + lr) * 32 + g * 8]);
    }
    __builtin_amdgcn_s_setprio(1);
#pragma unroll
    for (int m = 0; m < 4; m++)
#pragma unroll
      for (int n = 0; n < 4; n++)
        acc[m][n] = __builtin_amdgcn_mfma_f32_16x16x32_bf16(af[m], bfr[n], acc[m][n], 0, 0, 0);
    __builtin_amdgcn_s_setprio(0);
    __syncthreads();  // drains stage(cur^1) vmem + all waves' lds reads of cur
    cur ^= 1;
  }

  if constexpr (EPI == 2) {
#pragma unroll
    for (int m = 0; m < 4; m++)
#pragma unroll
      for (int n = 0; n < 4; n++)
#pragma unroll
        for (int r2 = 0; r2 < 4; r2++) {
          int row = bm + wr * 64 + m * 16 + g * 4 + r2;
          int col = bn + wc * 64 + n * 16 + lr;
          foutp[(size_t)row * DMODEL + col] = acc[m][n][r2] + bias[col];
        }
  } else {
    const bool dorope = (EPI == 0) || (bn < DMODEL);
#pragma unroll
    for (int m = 0; m < 4; m++)
#pragma unroll
      for (int n = 0; n < 4; n++)
#pragma unroll
        for (int r2 = 0; r2 < 4; r2++) {
          int row = bm + wr * 64 + m * 16 + g * 4 + r2;
          int col = bn + wc * 64 + n * 16 + lr;
          float v = acc[m][n][r2];
          float pv = __shfl_xor(v, 1);  // partner column (col^1)
          int bb = row >> 11, nn = row & (NSEQ - 1);
          if (dorope) {
            int hh = col >> 6, d = col & 63;
            f32x2 sc = cs[((row << 1) + (d >> 5)) * 16 + ((d >> 1) & 15)];
            float o = (d & 1) ? (pv * sc.y + v * sc.x) : (v * sc.x - pv * sc.y);
            if constexpr (EPI == 0) o *= 0.125f * 1.44269504088896f;  // scale * log2(e)
            out0[(((size_t)(bb * NH + hh)) * NSEQ + nn) * HD + d] = f2b(o);
          } else {
            int c2 = col - DMODEL;
            int hh = c2 >> 6, d = c2 & 63;
            out1[(((size_t)(bb * NH + hh)) * NSEQ + nn) * HD + d] = f2b(v);
          }
        }
  }
}

// ---------------- flash attention v3 ----------------
// grid 1024 (1D, XCD-swizzled so all 16 q-blocks of a (b,h) share an XCD's L2).
// 256 thr = 4 waves; wave owns 32 q rows (2 subtiles). KVBLK=64, dbuf LDS.
// S^T = mfma(K, Q): q=lr lane-local. Softmax in 2^x domain; defer-max THR=8;
// max via v_max3 tree; row-sum l via ones-MFMA (accL) on the idle MFMA pipe.
// PV: out^T = mfma(V^T, P^T); V-frags are single b128 reads from the
// permuted+swizzled Vtile layout. setprio(1) around both MFMA clusters.
__launch_bounds__(256, 4) __global__
void k_attn(const unsigned short* __restrict__ Q, const unsigned short* __restrict__ K,
            const unsigned short* __restrict__ VT, unsigned short* __restrict__ O) {
  __shared__ __align__(1024) unsigned short Kl[2][64 * 64];  // [kv][d], 16B-XOR swizzled
  __shared__ __align__(1024) unsigned short Vl[2][64 * 64];  // baked-permuted V tiles
  const int tid = threadIdx.x;
  const int wave = tid >> 6, lane = tid & 63;
  const int g = lane >> 4, lr = lane & 15;
  const int wid = ((blockIdx.x & 7) << 7) + (blockIdx.x >> 3);  // XCD swizzle (1024%8==0)
  const int qt = wid & 15, h = (wid >> 4) & 31, b = wid >> 9;
  const int bh = b * NH + h;
  const size_t headoff = (size_t)bh * NSEQ * HD;
  const int q0 = qt * 128 + wave * 32;

  // Q fragments in registers: qf[qsub][ks]
  bf16x8 qf[2][2];
#pragma unroll
  for (int qs = 0; qs < 2; qs++)
#pragma unroll
    for (int ks = 0; ks < 2; ks++)
      qf[qs][ks] = *(const bf16x8*)(Q + headoff + (size_t)(q0 + qs * 16 + lr) * HD + ks * 32 + g * 8);

  f32x4 accO[2][4];
#pragma unroll
  for (int qs = 0; qs < 2; qs++)
#pragma unroll
    for (int c = 0; c < 4; c++) accO[qs][c] = (f32x4){0.f, 0.f, 0.f, 0.f};
  f32x4 accL[2] = {(f32x4){0.f, 0.f, 0.f, 0.f}, (f32x4){0.f, 0.f, 0.f, 0.f}};
  float mrun[2] = {-1e30f, -1e30f};

  const unsigned short c1 = 0x3F80;  // bf16 1.0
  const bf16x8 ones = {(short)c1, (short)c1, (short)c1, (short)c1,
                       (short)c1, (short)c1, (short)c1, (short)c1};

  // K staged with inverse-swizzled per-lane global source (LDS dest linear);
  // V tiles are pre-permuted+swizzled in global, so V staging is linear.
  const int srow = tid >> 3;
  const unsigned short* kSrc = K + headoff + (size_t)srow * HD + (((tid & 7) ^ (srow & 7)) << 3);
  const unsigned short* vSrc = VT + (size_t)bh * (NCTX * HD) + tid * 8;

  auto stage = [&](int bi, int kv0) {
#pragma unroll
    for (int r = 0; r < 2; ++r) {
      async16(kSrc + (size_t)(kv0 + r * 32) * HD, &Kl[bi][(r * 4 + wave) * 512]);
      async16(vSrc + (size_t)kv0 * 64 + r * 2048, &Vl[bi][(r * 4 + wave) * 512]);
    }
  };

  stage(0, 0);
  __syncthreads();
  int cur = 0;

  for (int t = 0; t < NCTX / 64; ++t) {
    if (t < NCTX / 64 - 1) stage(cur ^ 1, (t + 1) * 64);

    const unsigned short* Kc = &Kl[cur][0];
    const unsigned short* Vc = &Vl[cur][0];

    // ---- S^T = K * Q^T  (rows kv, cols q) ----
    f32x4 s[2][4];
#pragma unroll
    for (int qs = 0; qs < 2; qs++)
#pragma unroll
      for (int sub = 0; sub < 4; sub++) s[qs][sub] = (f32x4){0.f, 0.f, 0.f, 0.f};
    __builtin_amdgcn_s_setprio(1);
#pragma unroll
    for (int sub = 0; sub < 4; ++sub) {
      const int kvr = sub * 16 + lr;
#pragma unroll
      for (int ks = 0; ks < 2; ++ks) {
        bf16x8 kf = *(const bf16x8*)(Kc + kvr * 64 + (((ks * 4 + g) ^ (kvr & 7)) << 3));
        s[0][sub] = __builtin_amdgcn_mfma_f32_16x16x32_bf16(kf, qf[0][ks], s[0][sub], 0, 0, 0);
        s[1][sub] = __builtin_amdgcn_mfma_f32_16x16x32_bf16(kf, qf[1][ks], s[1][sub], 0, 0, 0);
      }
    }
    __builtin_amdgcn_s_setprio(0);

    // ---- online softmax (2^x domain), P -> bf16 frags ----
    bf16x8 pb[2][2];
#pragma unroll
    for (int qs = 0; qs < 2; ++qs) {
      float t0 = max3f(s[qs][0][0], s[qs][0][1], s[qs][0][2]);
      float t1 = max3f(s[qs][0][3], s[qs][1][0], s[qs][1][1]);
      float t2 = max3f(s[qs][1][2], s[qs][1][3], s[qs][2][0]);
      float t3 = max3f(s[qs][2][1], s[qs][2][2], s[qs][2][3]);
      float t4 = max3f(s[qs][3][0], s[qs][3][1], s[qs][3][2]);
      float u0 = max3f(t0, t1, s[qs][3][3]);
      float u1 = max3f(t2, t3, t4);
      float tm = fmaxf(u0, u1);
      tm = fmaxf(tm, __shfl_xor(tm, 16));
      tm = fmaxf(tm, __shfl_xor(tm, 32));
      if (__any(tm > mrun[qs] + 8.0f)) {  // defer-max: rescale only on real growth
        float mnew = fmaxf(mrun[qs], tm);
        float corr = exp2a(mrun[qs] - mnew);
        accL[qs] *= corr;
#pragma unroll
        for (int c = 0; c < 4; c++) accO[qs][c] *= corr;
        mrun[qs] = mnew;
      }
#pragma unroll
      for (int sub = 0; sub < 4; sub++)
#pragma unroll
        for (int r2 = 0; r2 < 4; r2++) s[qs][sub][r2] = exp2a(s[qs][sub][r2] - mrun[qs]);
#pragma unroll
      for (int kg = 0; kg < 2; kg++) {
        u32x4 w;
        w.x = cvtpk(s[qs][2 * kg][0], s[qs][2 * kg][1]);
        w.y = cvtpk(s[qs][2 * kg][2], s[qs][2 * kg][3]);
        w.z = cvtpk(s[qs][2 * kg + 1][0], s[qs][2 * kg + 1][1]);
        w.w = cvtpk(s[qs][2 * kg + 1][2], s[qs][2 * kg + 1][3]);
        pb[qs][kg] = __builtin_bit_cast(bf16x8, w);
      }
    }

    // ---- PV: out^T += V^T * P^T;  l += 1^T * P^T (ones-MFMA) ----
    __builtin_amdgcn_s_setprio(1);
#pragma unroll
    for (int c = 0; c < 4; ++c) {
      const int d = c * 16 + lr;
#pragma unroll
      for (int kg = 0; kg < 2; ++kg) {
        bf16x8 vf = *(const bf16x8*)(Vc + d * 64 + ((kg * 32 + g * 8) ^ ((d & 7) << 3)));
        accO[0][c] = __builtin_amdgcn_mfma_f32_16x16x32_bf16(vf, pb[0][kg], accO[0][c], 0, 0, 0);
        accO[1][c] = __builtin_amdgcn_mfma_f32_16x16x32_bf16(vf, pb[1][kg], accO[1][c], 0, 0, 0);
      }
    }
    accL[0] = __builtin_amdgcn_mfma_f32_16x16x32_bf16(ones, pb[0][0], accL[0], 0, 0, 0);
    accL[0] = __builtin_amdgcn_mfma_f32_16x16x32_bf16(ones, pb[0][1], accL[0], 0, 0, 0);
    accL[1] = __builtin_amdgcn_mfma_f32_16x16x32_bf16(ones, pb[1][0], accL[1], 0, 0, 0);
    accL[1] = __builtin_amdgcn_mfma_f32_16x16x32_bf16(ones, pb[1][1], accL[1], 0, 0, 0);
    __builtin_amdgcn_s_setprio(0);
    __syncthreads();
    cur ^= 1;
  }

  // ---- epilogue: normalize (accL holds full row-sum, replicated), store bf16 ----
  const size_t obase = (size_t)b * NSEQ * DMODEL + (size_t)h * HD;
#pragma unroll
  for (int qs = 0; qs < 2; ++qs) {
    float inv = 1.0f / accL[qs][0];
    const int q = q0 + qs * 16 + lr;
#pragma unroll
    for (int c = 0; c < 4; ++c) {
      s16x4 o4;
#pragma unroll
      for (int r2 = 0; r2 < 4; r2++) o4[r2] = (short)f2b(accO[qs][c][r2] * inv);
      *(s16x4*)(O + obase + (size_t)q * DMODEL + c * 16 + 4 * g) = o4;
    }
  }
}

extern "C" void kernel_launch(void* const* d_in, const int* in_sizes, int n_in,
                              void* d_out, int out_size, void* d_ws, size_t ws_size,
                              hipStream_t stream) {
  const float* x = (const float*)d_in[0];
  const float* ctx = (const float*)d_in[1];
  const float* pos_map = (const float*)d_in[2];
  const float* ctx_pos = (const float*)d_in[3];
  const float* Wq = (const float*)d_in[4];
  const float* Wkv = (const float*)d_in[5];
  const float* Wout = (const float*)d_in[6];
  const float* bout = (const float*)d_in[7];
  float* outp = (float*)d_out;

  char* ws = (char*)d_ws;
  unsigned short* xbf = (unsigned short*)(ws + 0);           // 16 MB (dead after gemm<0>)
  unsigned short* vtbf = (unsigned short*)(ws + 0);          // 16 MB alias over xbf
  unsigned short* ctxbf = (unsigned short*)(ws + 16777216);  // 8 MB
  unsigned short* wqt = (unsigned short*)(ws + 25165824);    // 8 MB  [N][K]
  unsigned short* wkvt = (unsigned short*)(ws + 33554432);   // 8 MB  [4096][1024]
  unsigned short* woutt = (unsigned short*)(ws + 41943040);  // 8 MB
  unsigned short* qbf = (unsigned short*)(ws + 50331648);    // 16 MB [B][H][N][D]
  unsigned short* kbf = (unsigned short*)(ws + 67108864);    // 16 MB
  unsigned short* vbf = (unsigned short*)(ws + 83886080);    // 16 MB [B][H][N][D]
  unsigned short* attnbf = (unsigned short*)(ws + 100663296);// 16 MB [B*N][2048]
  f32x2* csq = (f32x2*)(ws + 117440512);                     // 1 MB
  f32x2* csk = (f32x2*)(ws + 118489088);                     // 1 MB

  k_cast<<<8192, 256, 0, stream>>>(x, xbf, 2097152);
  k_cast<<<4096, 256, 0, stream>>>(ctx, ctxbf, 1048576);
  dim3 tb(32, 8);
  k_tcast<<<dim3(64, 64), tb, 0, stream>>>(Wq, wqt, 2048, 2048);
  k_tcast<<<dim3(128, 32), tb, 0, stream>>>(Wkv, wkvt, 1024, 4096);
  k_tcast<<<dim3(64, 64), tb, 0, stream>>>(Wout, woutt, 2048, 2048);
  k_ropetab<<<512, 256, 0, stream>>>(pos_map, csq);
  k_ropetab<<<512, 256, 0, stream>>>(ctx_pos, csk);

  // Q = rope(x @ Wq) * 0.125*log2e -> [B][H][N][D]
  k_gemm<0><<<dim3(16, 32), 256, 0, stream>>>(xbf, wqt, qbf, nullptr, nullptr, csq, nullptr, 2048);
  // K,V = split(ctx @ Wkv); rope(K) -> [B][H][N][D]
  k_gemm<1><<<dim3(32, 32), 256, 0, stream>>>(ctxbf, wkvt, kbf, vbf, nullptr, csk, nullptr, 1024);
  // V -> permuted+swizzled V tiles (xbf is dead now; vtbf aliases it)
  k_vtrans<<<dim3(32, 64), 256, 0, stream>>>(vbf, vtbf);
  // attention -> attn_bf [B*N][2048]
  k_attn<<<1024, 256, 0, stream>>>(qbf, kbf, vtbf, attnbf);
  // out = attn @ Wout + bout (f32)
  k_gemm<2><<<dim3(16, 32), 256, 0, stream>>>(attnbf, woutt, nullptr, nullptr, outp, nullptr, bout, 2048);
}